// Round 11
// baseline (101.235 us; speedup 1.0000x reference)
//
#include <hip/hip_runtime.h>
#include <hip/hip_bf16.h>
#include <math.h>

#define BH_ 32
#define N_ 4096
#define D_ 64
#define SAMP_ 256
#define SC2_ 0.1803368801111244f   // SCALE * log2(e)
#define HPAD 68

typedef __attribute__((ext_vector_type(4))) float f32x4;
typedef __attribute__((ext_vector_type(8))) short bf16x8;
typedef __attribute__((ext_vector_type(4))) short bf16x4;

static __device__ __forceinline__ unsigned pack2(float a, float b) {
    union { __hip_bfloat162 h; unsigned u; } c;
    c.h = __float22bfloat162_rn(make_float2(a, b));
    return c.u;
}

static __device__ __forceinline__ bf16x8 cvt8v(f32x4 a, f32x4 b) {
    union { unsigned u[4]; bf16x8 v; } r;
    r.u[0] = pack2(a[0], a[1]); r.u[1] = pack2(a[2], a[3]);
    r.u[2] = pack2(b[0], b[1]); r.u[3] = pack2(b[2], b[3]);
    return r.v;
}

static __device__ __forceinline__ bf16x8 cvt8(const float* p) {
    return cvt8v(*(const f32x4*)p, *(const f32x4*)(p + 4));
}

// ---------------- 1. LSH hash (working) -------------------------------------
__global__ __launch_bounds__(128) void hash_kernel(
    const float* __restrict__ q, const float* __restrict__ k,
    const float* __restrict__ pd,
    unsigned char* __restrict__ qbuck, unsigned char* __restrict__ kbuck)
{
    extern __shared__ char smraw[];
    float*  Xs  = (float*)smraw;
    double* Pdl = (double*)(smraw + 128 * HPAD * 4);

    int tid = threadIdx.x;
    const float* src = blockIdx.y ? k : q;
    unsigned char* dst = blockIdx.y ? kbuck : qbuck;
    size_t tok0 = (size_t)blockIdx.x * 128;

    {
        int d = tid >> 1, r0 = (tid & 1) * 4;
#pragma unroll
        for (int j = 0; j < 4; ++j)
            Pdl[d * 8 + r0 + j] = (double)pd[d * 8 + r0 + j];
    }
    {
        const float4* src4 = (const float4*)(src + tok0 * D_);
        for (int i = tid; i < 128 * 16; i += 128) {
            int r = i >> 4, c = i & 15;
            *(float4*)&Xs[r * HPAD + c * 4] = src4[i];
        }
    }
    __syncthreads();

    float xr[64];
#pragma unroll
    for (int c = 0; c < 16; ++c)
        *(f32x4*)&xr[c * 4] = *(const f32x4*)&Xs[tid * HPAD + c * 4];

    double acc[8];
#pragma unroll
    for (int r = 0; r < 8; ++r) acc[r] = 0.0;
#pragma unroll
    for (int d = 0; d < 64; ++d) {
        double x = (double)xr[d];
        const double* pr = Pdl + d * 8;
#pragma unroll
        for (int r = 0; r < 8; ++r) acc[r] += x * pr[r];
    }
    int bin = 0;
#pragma unroll
    for (int r = 0; r < 8; ++r)
        if (acc[r] > 0.0) bin |= (1 << r);
    dst[tok0 + tid] = (unsigned char)(bin ^ (bin >> 1));
}

// ---------------- 2. stable counting sort (working) -------------------------
__global__ __launch_bounds__(256) void sort_kernel(
    const unsigned char* __restrict__ qbuck,
    const unsigned char* __restrict__ kbuck,
    int* __restrict__ q_idx, int* __restrict__ k_idx)
{
    __shared__ unsigned short hist[64][256];
    __shared__ unsigned int   binstart[256];
    __shared__ alignas(16) unsigned char bl[N_];

    int bh = blockIdx.x, tensor = blockIdx.y;
    const unsigned char* buck = (tensor ? kbuck : qbuck) + bh * N_;
    int* idx_out = (tensor ? k_idx : q_idx) + bh * N_;
    int t = threadIdx.x;

    ((uint4*)bl)[t] = ((const uint4*)buck)[t];
    {
        uint4* h4 = (uint4*)&hist[0][0];
        for (int i = t; i < 2048; i += 256) h4[i] = make_uint4(0, 0, 0, 0);
    }
    __syncthreads();

    if (t < 64) {
        for (int u = 0; u < 64; ++u) hist[t][bl[t * 64 + u]]++;
    }
    __syncthreads();

    {
        unsigned run = 0;
        for (int tt = 0; tt < 64; ++tt) {
            unsigned c = hist[tt][t];
            hist[tt][t] = (unsigned short)run;
            run += c;
        }
        binstart[t] = run;
    }
    __syncthreads();

    if (t < 64) {
        unsigned b0 = binstart[t*4], b1 = binstart[t*4+1],
                 b2 = binstart[t*4+2], b3 = binstart[t*4+3];
        unsigned s = b0 + b1 + b2 + b3, p = s;
#pragma unroll
        for (int d = 1; d < 64; d <<= 1) {
            unsigned y = __shfl_up(p, d);
            if (t >= d) p += y;
        }
        unsigned e = p - s;
        binstart[t*4]   = e;
        binstart[t*4+1] = e + b0;
        binstart[t*4+2] = e + b0 + b1;
        binstart[t*4+3] = e + b0 + b1 + b2;
    }
    __syncthreads();

    if (t < 64) {
        for (int u = 0; u < 64; ++u) {
            int tok = t * 64 + u;
            int b = bl[tok];
            int pos = (int)(binstart[b] + hist[t][b]);
            hist[t][b]++;
            idx_out[pos] = tok;
        }
    }
}

// ---------------- 3. fused attention: 32 waves/CU ---------------------------
// 1024 wgs x 512 thr (8 waves x 16 queries). 4 phases of 128 keys (2 block +
// 2 sampled); 32KB LDS/wg -> 4 wgs/CU x 8 waves = 32 waves/CU (8/SIMD), all
// 256 CUs covered. Per-wave state halved vs R10 (o 16 + qf 8 regs) to fit
// the 64-VGPR cap of __launch_bounds__(512,8) WITHOUT spilling.
// exp folded: e = exp2(s*SCALE*log2e + bias2), bias2 = log2(16) = 4.0 exact.
// K LDS: [kt(8)][ks(2)][lg(4)][ll(16)][8] shorts; staged conflict-free
// (krow = tid&127). V LDS: 4 x tr-subtile groups (verified R4-R10 image).
__global__ __launch_bounds__(512, 8) void fused_attn(
    const float* __restrict__ query, const float* __restrict__ key,
    const float* __restrict__ value, const int* __restrict__ q_idx,
    const int* __restrict__ k_idx, const int* __restrict__ sampled,
    float* __restrict__ out)
{
    __shared__ __align__(16) short Ksm[8192];   // 16 KB (128 keys x 64 d)
    __shared__ __align__(16) short Vsm[8192];   // 16 KB
    int wgid = blockIdx.x;
    int wg = (wgid & 7) * 128 + (wgid >> 3);    // bijective XCD swizzle
    int bh = wg >> 5, sub = wg & 31;            // sub: 128-query slice
    int tid = threadIdx.x, w = tid >> 6, l = tid & 63, lg = l >> 4, ll = l & 15;
    size_t base = (size_t)bh * N_;

    const int* kidxA = k_idx + base + (sub >> 1) * 256;
    const int* kidxB = sampled + bh * SAMP_;

    // staging decomposition
    int krow = tid & 127, kd0 = (tid >> 7) * 16;
    int koff = (krow >> 4) * 1024 + (kd0 >> 5) * 512 + ((kd0 >> 3) & 3) * 128
             + (krow & 15) * 8;
    int l6 = tid & 63, i6 = tid >> 6;
    int vrow = (i6 >> 2) * 32 + (i6 & 3) * 8 + (l6 >> 5) * 4 + ((l6 >> 1) & 3);
    int vd   = ((l6 >> 3) & 3) * 16 + (l6 & 1) * 8;

    // Q fragment (wave owns 16 queries)
    const int* qidx = q_idx + base + sub * 128 + w * 16;
    int qr = qidx[ll];
    const float* qp = query + (base + (size_t)qr) * D_ + lg * 8;
    bf16x8 qf[2] = { cvt8(qp), cvt8(qp + 32) };

    f32x4 o[4];
#pragma unroll
    for (int dt = 0; dt < 4; ++dt) { f32x4 z = {0.f,0.f,0.f,0.f}; o[dt] = z; }
    float lsum = 0.f;
    unsigned vtr = (unsigned)(unsigned long long)(void*)&Vsm[0] + lg * 512 + ll * 8;

    // stage helper (macro to keep everything in registers, no arrays)
#define STAGE_(KI, VI0, VI1) do { \
        const float* kp_ = key + (base + (size_t)(KI)) * D_ + kd0; \
        f32x4 ka_ = *(const f32x4*)kp_,       kb_ = *(const f32x4*)(kp_ + 4); \
        f32x4 kc_ = *(const f32x4*)(kp_ + 8), kd_ = *(const f32x4*)(kp_ + 12); \
        const float* vp0_ = value + (base + (size_t)(VI0)) * D_ + vd; \
        const float* vp1_ = value + (base + (size_t)(VI1)) * D_ + vd; \
        f32x4 va_ = *(const f32x4*)vp0_, vb_ = *(const f32x4*)(vp0_ + 4); \
        f32x4 vc_ = *(const f32x4*)vp1_, vd_ = *(const f32x4*)(vp1_ + 4); \
        *(bf16x8*)&Ksm[koff]        = cvt8v(ka_, kb_); \
        *(bf16x8*)&Ksm[koff + 128]  = cvt8v(kc_, kd_); \
        *(bf16x8*)&Vsm[tid * 8]        = cvt8v(va_, vb_); \
        *(bf16x8*)&Vsm[4096 + tid * 8] = cvt8v(vc_, vd_); } while (0)

#define COMPUTE_(BIAS2) do { \
        _Pragma("unroll") \
        for (int hgi = 0; hgi < 4; ++hgi) { \
            unsigned pbu[4]; \
            __builtin_amdgcn_s_setprio(1); \
            _Pragma("unroll") \
            for (int t = 0; t < 2; ++t) { \
                int kt = hgi * 2 + t; \
                f32x4 s = {0.f,0.f,0.f,0.f}; \
                _Pragma("unroll") \
                for (int ks = 0; ks < 2; ++ks) { \
                    bf16x8 a = *(const bf16x8*)&Ksm[kt * 1024 + ks * 512 + lg * 128 + ll * 8]; \
                    s = __builtin_amdgcn_mfma_f32_16x16x32_bf16(a, qf[ks], s, 0, 0, 0); \
                } \
                __builtin_amdgcn_s_setprio(0); \
                f32x4 e; \
                _Pragma("unroll") \
                for (int r = 0; r < 4; ++r) e[r] = exp2f(fmaf(s[r], SC2_, (BIAS2))); \
                lsum += (e[0] + e[1]) + (e[2] + e[3]); \
                pbu[t*2]   = pack2(e[0], e[1]); \
                pbu[t*2+1] = pack2(e[2], e[3]); \
                __builtin_amdgcn_s_setprio(1); \
            } \
            bf16x8 pb; \
            { union { unsigned u[4]; bf16x8 v; } cc_; \
              cc_.u[0]=pbu[0]; cc_.u[1]=pbu[1]; cc_.u[2]=pbu[2]; cc_.u[3]=pbu[3]; pb=cc_.v; } \
            bf16x4 tr[4][2]; \
            _Pragma("unroll") \
            for (int dt = 0; dt < 4; ++dt) { \
                asm volatile("ds_read_b64_tr_b16 %0, %1 offset:%2" \
                             : "=v"(tr[dt][0]) : "v"(vtr), "i"(hgi * 4096 + dt * 128)); \
                asm volatile("ds_read_b64_tr_b16 %0, %1 offset:%2" \
                             : "=v"(tr[dt][1]) : "v"(vtr), "i"(hgi * 4096 + dt * 128 + 2048)); \
            } \
            asm volatile("s_waitcnt lgkmcnt(0)" ::: "memory"); \
            __builtin_amdgcn_sched_barrier(0); \
            _Pragma("unroll") \
            for (int dt = 0; dt < 4; ++dt) { \
                union { bf16x4 h[2]; bf16x8 v; } va2; \
                va2.h[0] = tr[dt][0]; va2.h[1] = tr[dt][1]; \
                o[dt] = __builtin_amdgcn_mfma_f32_16x16x32_bf16(va2.v, pb, o[dt], 0, 0, 0); \
            } \
            __builtin_amdgcn_s_setprio(0); \
        } } while (0)

    // ---- 4 phases: A0 A1 (block keys, bias2 0) / B0 B1 (sampled, bias2 4)
    int kI = kidxA[krow], vI0 = kidxA[vrow], vI1 = kidxA[64 + vrow];

    STAGE_(kI, vI0, vI1);
    __syncthreads();
    kI = kidxA[128 + krow]; vI0 = kidxA[128 + vrow]; vI1 = kidxA[192 + vrow];
    COMPUTE_(0.f);
    __syncthreads();

    STAGE_(kI, vI0, vI1);
    __syncthreads();
    kI = kidxB[krow]; vI0 = kidxB[vrow]; vI1 = kidxB[64 + vrow];
    COMPUTE_(0.f);
    __syncthreads();

    STAGE_(kI, vI0, vI1);
    __syncthreads();
    kI = kidxB[128 + krow]; vI0 = kidxB[128 + vrow]; vI1 = kidxB[192 + vrow];
    COMPUTE_(4.f);
    __syncthreads();

    STAGE_(kI, vI0, vI1);
    __syncthreads();
    COMPUTE_(4.f);
#undef STAGE_
#undef COMPUTE_

    // ---- row-sum over lg groups; epilogue out = o / l
    lsum += __shfl_xor(lsum, 16);
    lsum += __shfl_xor(lsum, 32);

    float dn = 1.f / lsum;
    float* orow = out + (base + (size_t)qr) * D_ + lg * 4;
#pragma unroll
    for (int dt = 0; dt < 4; ++dt) {
        f32x4 v = o[dt] * dn;
        *(f32x4*)&orow[dt * 16] = v;
    }
}

// ---------------------------------------------------------------------------
extern "C" void kernel_launch(void* const* d_in, const int* in_sizes, int n_in,
                              void* d_out, int out_size, void* d_ws, size_t ws_size,
                              hipStream_t stream)
{
    const float* query = (const float*)d_in[0];
    const float* key   = (const float*)d_in[1];
    const float* value = (const float*)d_in[2];
    const float* pd    = (const float*)d_in[3];
    const int*   samp  = (const int*)d_in[4];
    float* out = (float*)d_out;

    char* ws = (char*)d_ws;
    unsigned char* qbuck = (unsigned char*)ws;                 // 128 KB
    unsigned char* kbuck = qbuck + (size_t)BH_ * N_;           // 128 KB
    int* q_idx = (int*)(ws + 262144);                          // 512 KB
    int* k_idx = (int*)(ws + 262144 + 524288);                 // 512 KB

    size_t hash_lds = 128 * HPAD * 4 + 512 * 8;
    hipLaunchKernelGGL(hash_kernel, dim3(BH_ * N_ / 128, 2), dim3(128),
                       hash_lds, stream, query, key, pd, qbuck, kbuck);
    hipLaunchKernelGGL(sort_kernel, dim3(BH_, 2), dim3(256), 0, stream,
                       qbuck, kbuck, q_idx, k_idx);
    hipLaunchKernelGGL(fused_attn, dim3(1024), dim3(512), 0, stream,
                       query, key, value, q_idx, k_idx, samp, out);
}